// Round 18
// baseline (2061.740 us; speedup 1.0000x reference)
//
#include <hip/hip_runtime.h>
#include <hip/hip_bf16.h>
#include <hip/hip_fp8.h>
#include <cstdint>

typedef __bf16 bf16_t;
typedef __bf16 bf16x4 __attribute__((ext_vector_type(4)));
typedef __bf16 bf16x8 __attribute__((ext_vector_type(8)));
typedef float f32x4 __attribute__((ext_vector_type(4)));
typedef unsigned char u8;

#define BATCH 4096
#define DIN   1024
#define HID   2048
#define DOUT  1000
#define NITER 50
#define LR    0.001f

#define BM 128
#define BN 128
#define BK 32
#define NBUF 4

// async global -> LDS, 16 B per lane. LDS dest is wave-uniform base + lane*16.
#define GLDS(g, l)                                                        \
    __builtin_amdgcn_global_load_lds(                                     \
        (const __attribute__((address_space(1))) void*)(g),               \
        (__attribute__((address_space(3))) void*)(l), 16, 0, 0)

#define WAITVM(N) asm volatile("s_waitcnt vmcnt(" #N ")" ::: "memory")
#define BAR()     __builtin_amdgcn_s_barrier()
#define SCHEDB()  __builtin_amdgcn_sched_barrier(0)

__device__ __forceinline__ u8 f32_to_fp8(float f) {
    __hip_fp8_e4m3 h(f);               // OCP e4m3fn on gfx950
    return (u8)h.__x;
}

// ---------------------------------------------------------------------------
// R17 champion (1816 us) with fp8 e4m3 GEMM operands (single variable).
// R17 post-mortem: b128 fragment reads were already at the structural bank
// floor; LDS-read VOLUME (~15 us/iter of 33) is the dominant term.  fp8
// halves it: e_x, Wg, Wc stored fp8; MFMA = f32_16x16x32_fp8_fp8 (i64
// operands, same fragment geometry, C/D layout dtype-independent).
// States stay bf16 (u,z,ey,xbf); energy computed from f32 pre-quantization.
// LDS tiles 4 KB each; staging: waves 0-3 stage A (1 GLDS/thread/tile),
// waves 4-7 stage B; counted vmcnt rescales 4/4/0 -> 2/2/0.
// Fragment reads are ds_read_b64 at the 4-cycle bank floor (derived).
// Everything else identical to R17: modes, epilogues, grids, ping-pong.
// MODE: 0 = UZ, 1 = UZ first (seed from biases), 2 = Z-only final.
// ---------------------------------------------------------------------------
template <int MODE>
__global__ __launch_bounds__(512) void pc_gemm(
    const u8* __restrict__ Aex, const u8* __restrict__ wg,
    const u8* __restrict__ wc,
    const bf16_t* __restrict__ xbf, const float* __restrict__ bias_g,
    const float* __restrict__ bias_o,
    u8* __restrict__ exnext, bf16_t* __restrict__ u,
    bf16_t* __restrict__ z, bf16_t* __restrict__ ey,
    float* __restrict__ yout, float* __restrict__ energy)
{
    __shared__ __align__(16) u8 sA[NBUF][BM * BK];   // 4 KB per buffer
    __shared__ __align__(16) u8 sB[NBUF][BN * BK];
    __shared__ float red[8];

    const int t    = threadIdx.x;
    const int lane = t & 63;
    const int wave = t >> 6;        // 0..7
    const int wm   = wave >> 2;     // wave row (0..1) -> 64 rows
    const int wn   = wave & 3;      // wave col (0..3) -> 32 cols
    const int m0   = blockIdx.x * BM;
    const int lr   = lane & 15;
    const int lkb  = (lane >> 4) * 8;   // byte offset of k-chunk (8 fp8)

    int role, n0;
    const u8 *Bop;
    if constexpr (MODE == 2) {
        role = 1; n0 = (int)blockIdx.y * BN; Bop = wc;
    } else {
        role = (int)blockIdx.y >= 8; n0 = ((int)blockIdx.y & 7) * BN;
        Bop = role ? wc : wg;
    }
    const int K = DIN;   // bytes per row (fp8)

    f32x4 acc[4][2] = {};

    // staging: waves 0-3 stage the A tile (128 x 32 B = 4 KB; wave w4 rows
    // [32*w4, 32*w4+32), lane l -> row 32*w4 + l/2, byte-col (l&1)*16);
    // waves 4-7 stage B identically.  1 GLDS (16 B) per thread per tile.
    const int w4   = wave & 3;
    const bool isB = wave >= 4;
    const int srow = w4 * 32 + (lane >> 1);
    const int scol = (lane & 1) * 16;
    const u8* gOp = isB ? (Bop + (int64_t)(n0 + srow) * K + scol)
                        : (Aex + (int64_t)(m0 + srow) * K + scol);

    auto stage = [&](int tile, int buf) {
        const int64_t ko = (int64_t)tile * BK;   // BK bytes
        if (isB) GLDS(gOp + ko, &sB[buf][w4 * 1024]);
        else     GLDS(gOp + ko, &sA[buf][w4 * 1024]);
    };

    auto compute = [&](int buf) {
        long af[4], bfr[2];
#pragma unroll
        for (int mi = 0; mi < 4; ++mi)
            af[mi] = *reinterpret_cast<const long*>(
                &sA[buf][(wm * 64 + mi * 16 + lr) * BK + lkb]);
#pragma unroll
        for (int ni = 0; ni < 2; ++ni)
            bfr[ni] = *reinterpret_cast<const long*>(
                &sB[buf][(wn * 32 + ni * 16 + lr) * BK + lkb]);
#pragma unroll
        for (int mi = 0; mi < 4; ++mi)
#pragma unroll
            for (int ni = 0; ni < 2; ++ni)
                acc[mi][ni] = __builtin_amdgcn_mfma_f32_16x16x32_fp8_fp8(
                    af[mi], bfr[ni], acc[mi][ni], 0, 0, 0);
    };

    const int npairs = (K / BK) / 2;       // 16
    stage(0, 0); stage(1, 1); stage(2, 2); stage(3, 3);   // 4 loads/thread

    for (int p = 0; p < npairs - 2; ++p) {
        const int t0 = 2 * p;
        WAITVM(2);               // pair p landed; pair p+1 still flying
        BAR();
        SCHEDB();
        compute(t0 & 3);
        compute((t0 + 1) & 3);
        BAR();
        stage(t0 + 4, t0 & 3);   // vmcnt never drains to 0 in loop
        stage(t0 + 5, (t0 + 1) & 3);
    }
    {
        const int t0 = 2 * npairs - 4;
        WAITVM(2); BAR(); SCHEDB();
        compute(t0 & 3); compute((t0 + 1) & 3);
    }
    {
        const int t0 = 2 * npairs - 2;
        WAITVM(0); BAR(); SCHEDB();
        compute(t0 & 3); compute((t0 + 1) & 3);
    }

    // epilogue: C mapping col=lane&15, row=(lane>>4)*4+j
    float esum = 0.0f;
    const int prow = (lane >> 4) * 4;
#pragma unroll
    for (int mi = 0; mi < 4; ++mi) {
#pragma unroll
        for (int ni = 0; ni < 2; ++ni) {
            const int col = n0 + wn * 32 + ni * 16 + lr;
#pragma unroll
            for (int j = 0; j < 4; ++j) {
                const int row = m0 + wm * 64 + mi * 16 + prow + j;
                const float v = acc[mi][ni][j];
                const float D = LR * v;
                if (role == 0) {
                    // U role: u += D; e_x' = x - sigmoid(u); energy
                    const int64_t idx = (int64_t)row * DIN + col;
                    const float un =
                        (MODE == 1 ? bias_g[col] : (float)u[idx]) + D;
                    u[idx] = (bf16_t)un;
                    const float xp = 1.0f / (1.0f + __expf(-un));
                    const float e  = (float)xbf[idx] - xp;
                    exnext[idx] = f32_to_fp8(e);
                    esum += e * e;
                } else if (col < DOUT) {
                    // Z role: z += D; e_y = (1+LR)e_y - D; energy
                    const int64_t idx = (int64_t)row * 1024 + col;
                    const float zn =
                        (MODE == 1 ? bias_o[col] : (float)z[idx]) + D;
                    const float eyn = (MODE == 1)
                        ? -zn
                        : (1.0f + LR) * (float)ey[idx] - D;
                    if constexpr (MODE == 2) {
                        yout[(int64_t)row * DOUT + col] =
                            (1.0f + LR) * eyn + zn;
                    } else {
                        z[idx]  = (bf16_t)zn;
                        ey[idx] = (bf16_t)eyn;
                    }
                    esum += eyn * eyn;
                }
            }
        }
    }
#pragma unroll
    for (int off = 32; off; off >>= 1) esum += __shfl_down(esum, off, 64);
    if (lane == 0) red[wave] = esum;
    __syncthreads();
    if (t == 0) {
        float s = 0.0f;
#pragma unroll
        for (int w = 0; w < 8; ++w) s += red[w];
        atomicAdd(energy, s);
    }
}

// ---------------------------------------------------------------------------
// setup: Wg = W_rec^T W_rec (role 0), Wc = W_out W_rec (role 1); K = 2048.
// bf16 GEMM core (R6-proven), epilogue stores fp8.  Runs once.
// ---------------------------------------------------------------------------
__global__ __launch_bounds__(512) void setup_gemm(
    const bf16_t* __restrict__ wrecT, const bf16_t* __restrict__ woutP,
    u8* __restrict__ wg, u8* __restrict__ wc)
{
    __shared__ __align__(16) bf16_t sA[4][128 * BK];
    __shared__ __align__(16) bf16_t sB[4][128 * BK];

    const int t    = threadIdx.x;
    const int lane = t & 63;
    const int wave = t >> 6;
    const int wm   = wave >> 2;
    const int wn   = wave & 3;
    const int m0   = blockIdx.x * 128;
    const int role = (int)blockIdx.y >= 8;
    const int n0   = ((int)blockIdx.y & 7) * 128;
    const int lr   = lane & 15;
    const int lkb  = (lane >> 4) * 8;
    const int prow = (lane >> 4) * 4;

    f32x4 acc[4][2] = {};

    const int srow = wave * 16 + (lane >> 2);
    const int scol = (lane & 3) * 8;
    const bf16_t* gA = (role ? woutP : wrecT) + (int64_t)(m0 + srow) * HID + scol;
    const bf16_t* gB = wrecT + (int64_t)(n0 + srow) * HID + scol;

    auto stage = [&](int tile, int buf) {
        const int64_t ko = (int64_t)tile * BK;
        GLDS(gA + ko, &sA[buf][wave * 512]);
        GLDS(gB + ko, &sB[buf][wave * 512]);
    };
    auto compute = [&](int buf) {
        bf16x8 af[4], bfr[2];
#pragma unroll
        for (int mi = 0; mi < 4; ++mi)
            af[mi] = *reinterpret_cast<const bf16x8*>(
                &sA[buf][(wm * 64 + mi * 16 + lr) * BK + lkb]);
#pragma unroll
        for (int ni = 0; ni < 2; ++ni)
            bfr[ni] = *reinterpret_cast<const bf16x8*>(
                &sB[buf][(wn * 32 + ni * 16 + lr) * BK + lkb]);
#pragma unroll
        for (int mi = 0; mi < 4; ++mi)
#pragma unroll
            for (int ni = 0; ni < 2; ++ni)
                acc[mi][ni] = __builtin_amdgcn_mfma_f32_16x16x32_bf16(
                    af[mi], bfr[ni], acc[mi][ni], 0, 0, 0);
    };

    const int npairs = (HID / BK) / 2;   // 32
    stage(0, 0); stage(1, 1); stage(2, 2); stage(3, 3);
    for (int p = 0; p < npairs - 2; ++p) {
        const int t0 = 2 * p;
        WAITVM(4); BAR(); SCHEDB();
        compute(t0 & 3); compute((t0 + 1) & 3);
        BAR();
        stage(t0 + 4, t0 & 3); stage(t0 + 5, (t0 + 1) & 3);
    }
    {
        const int t0 = 2 * npairs - 4;
        WAITVM(4); BAR(); SCHEDB();
        compute(t0 & 3); compute((t0 + 1) & 3);
    }
    {
        const int t0 = 2 * npairs - 2;
        WAITVM(0); BAR(); SCHEDB();
        compute(t0 & 3); compute((t0 + 1) & 3);
    }

    u8* cout = role ? wc : wg;
#pragma unroll
    for (int mi = 0; mi < 4; ++mi)
#pragma unroll
        for (int ni = 0; ni < 2; ++ni) {
            const int col = n0 + wn * 32 + ni * 16 + lr;
#pragma unroll
            for (int j = 0; j < 4; ++j) {
                const int row = m0 + wm * 64 + mi * 16 + prow + j;
                cout[(int64_t)row * 1024 + col] = f32_to_fp8(acc[mi][ni][j]);
            }
        }
}

// W_rec [HID][DIN] f32 -> bf16 transpose [DIN][HID]
__global__ void conv_wrec(const float* __restrict__ W, bf16_t* __restrict__ WbT)
{
    __shared__ float tile[32][33];
    const int tx = threadIdx.x & 31;
    const int ty = threadIdx.x >> 5; // 0..7
    const int c0 = blockIdx.x * 32;  // DIN
    const int r0 = blockIdx.y * 32;  // HID
#pragma unroll
    for (int rr = ty; rr < 32; rr += 8)
        tile[rr][tx] = W[(int64_t)(r0 + rr) * DIN + c0 + tx];
    __syncthreads();
#pragma unroll
    for (int rr = ty; rr < 32; rr += 8)
        WbT[(int64_t)(c0 + rr) * HID + r0 + tx] = (bf16_t)tile[tx][rr];
}

// W_out [DOUT][HID] f32 -> bf16 [1024][HID], rows >= DOUT zero-padded
__global__ void conv_wout(const float* __restrict__ W, bf16_t* __restrict__ Wb)
{
    const int i = blockIdx.x * 256 + threadIdx.x; // over 1024*2048
    const int r = i >> 11;
    const int c = i & 2047;
    Wb[i] = (r < DOUT) ? (bf16_t)W[(int64_t)r * HID + c] : (bf16_t)0.0f;
}

// iteration 0: e_x0 = x - sigmoid(b_gen) (fp8, + energy); also x -> bf16 copy
__global__ void ex0_kernel(const float* __restrict__ x,
                           const float* __restrict__ bias_g,
                           u8* __restrict__ ex, bf16_t* __restrict__ xbf,
                           float* __restrict__ energy)
{
    __shared__ float red[4];
    const int t = threadIdx.x, lane = t & 63, wave = t >> 6;
    const int i = (blockIdx.x * 256 + t) * 4;
    const int c0 = i & (DIN - 1);
    const float4 v = *reinterpret_cast<const float4*>(&x[i]);
    bf16x4 xo = {(bf16_t)v.x, (bf16_t)v.y, (bf16_t)v.z, (bf16_t)v.w};
    *reinterpret_cast<bf16x4*>(&xbf[i]) = xo;
    float e[4];
    const float b0 = bias_g[c0], b1 = bias_g[c0 + 1],
                b2 = bias_g[c0 + 2], b3 = bias_g[c0 + 3];
    e[0] = v.x - 1.0f / (1.0f + __expf(-b0));
    e[1] = v.y - 1.0f / (1.0f + __expf(-b1));
    e[2] = v.z - 1.0f / (1.0f + __expf(-b2));
    e[3] = v.w - 1.0f / (1.0f + __expf(-b3));
    unsigned int pk = (unsigned int)f32_to_fp8(e[0])
                    | ((unsigned int)f32_to_fp8(e[1]) << 8)
                    | ((unsigned int)f32_to_fp8(e[2]) << 16)
                    | ((unsigned int)f32_to_fp8(e[3]) << 24);
    *reinterpret_cast<unsigned int*>(&ex[i]) = pk;
    float esum = e[0]*e[0] + e[1]*e[1] + e[2]*e[2] + e[3]*e[3];
#pragma unroll
    for (int off = 32; off; off >>= 1) esum += __shfl_down(esum, off, 64);
    if (lane == 0) red[wave] = esum;
    __syncthreads();
    if (t == 0) atomicAdd(energy, red[0] + red[1] + red[2] + red[3]);
}

__global__ void finalize_kernel(const float* __restrict__ energy,
                                float* __restrict__ out)
{
    out[0] = energy[0] * (1.0f / ((float)BATCH * (float)NITER));
}

extern "C" void kernel_launch(void* const* d_in, const int* in_sizes, int n_in,
                              void* d_out, int out_size, void* d_ws, size_t ws_size,
                              hipStream_t stream)
{
    (void)in_sizes; (void)n_in; (void)out_size; (void)ws_size;
    const float* x        = (const float*)d_in[0];
    const float* W_rec    = (const float*)d_in[1];
    const float* W_out    = (const float*)d_in[2];
    const float* bias_out = (const float*)d_in[3];
    const float* bias_gen = (const float*)d_in[4];
    float* y = (float*)d_out; // [BATCH*DOUT] then [1] energy

    char* ws = (char*)d_ws;
    size_t off = 0;
    bf16_t* u     = (bf16_t*)(ws + off);  off += (size_t)BATCH * DIN * 2;   // 8 MB
    bf16_t* z     = (bf16_t*)(ws + off);  off += (size_t)BATCH * 1024 * 2;  // 8 MB
    bf16_t* ey    = (bf16_t*)(ws + off);  off += (size_t)BATCH * 1024 * 2;  // 8 MB
    bf16_t* xbf   = (bf16_t*)(ws + off);  off += (size_t)BATCH * DIN * 2;   // 8 MB
    u8* exA       = (u8*)(ws + off);      off += (size_t)BATCH * DIN;       // 4 MB
    u8* exB       = (u8*)(ws + off);      off += (size_t)BATCH * DIN;       // 4 MB
    bf16_t* wrecT = (bf16_t*)(ws + off);  off += (size_t)DIN * HID * 2;     // 4 MB
    bf16_t* woutP = (bf16_t*)(ws + off);  off += (size_t)1024 * HID * 2;    // 4 MB
    u8* wg        = (u8*)(ws + off);      off += (size_t)1024 * 1024;       // 1 MB
    u8* wc        = (u8*)(ws + off);      off += (size_t)1024 * 1024;       // 1 MB
    float* energy = (float*)(ws + off);   off += 256;                       // 50 MB

    hipMemsetAsync(energy, 0, 4, stream);

    conv_wrec<<<dim3(DIN / 32, HID / 32), 256, 0, stream>>>(W_rec, wrecT);
    conv_wout<<<(1024 * HID) / 256, 256, 0, stream>>>(W_out, woutP);
    setup_gemm<<<dim3(8, 16), 512, 0, stream>>>(wrecT, woutP, wg, wc);
    ex0_kernel<<<(BATCH * DIN) / 1024, 256, 0, stream>>>(x, bias_gen, exA,
                                                         xbf, energy);

    u8* exbuf[2] = {exA, exB};
    for (int it = 0; it < NITER; ++it) {
        const u8* src = exbuf[it & 1];
        u8* dst = exbuf[(it & 1) ^ 1];
        if (it == 0)
            pc_gemm<1><<<dim3(BATCH / BM, 16), 512, 0, stream>>>(
                src, wg, wc, xbf, bias_gen, bias_out,
                dst, u, z, ey, nullptr, energy);
        else if (it < NITER - 1)
            pc_gemm<0><<<dim3(BATCH / BM, 16), 512, 0, stream>>>(
                src, wg, wc, xbf, bias_gen, bias_out,
                dst, u, z, ey, nullptr, energy);
        else
            pc_gemm<2><<<dim3(BATCH / BM, 8), 512, 0, stream>>>(
                src, wg, wc, xbf, bias_gen, bias_out,
                nullptr, u, z, ey, y, energy);
    }
    finalize_kernel<<<1, 1, 0, stream>>>(energy, y + (size_t)BATCH * DOUT);
}

// Round 19
// 1928.699 us; speedup vs baseline: 1.0690x; 1.0690x over previous
//
#include <hip/hip_runtime.h>
#include <hip/hip_bf16.h>
#include <cstdint>

typedef __bf16 bf16_t;
typedef __bf16 bf16x4 __attribute__((ext_vector_type(4)));
typedef __bf16 bf16x8 __attribute__((ext_vector_type(8)));
typedef float f32x4 __attribute__((ext_vector_type(4)));

#define BATCH 4096
#define DIN   1024
#define HID   2048
#define DOUT  1000
#define NITER 50
#define LR    0.001f

#define BM 128
#define BN 128
#define BK 32
#define NBUF 3

// async global -> LDS, 16 B per lane. LDS dest is wave-uniform base + lane*16.
#define GLDS(g, l)                                                        \
    __builtin_amdgcn_global_load_lds(                                     \
        (const __attribute__((address_space(1))) void*)(g),               \
        (__attribute__((address_space(3))) void*)(l), 16, 0, 0)

#define WAITVM(N) asm volatile("s_waitcnt vmcnt(" #N ")" ::: "memory")
#define BAR()     __builtin_amdgcn_s_barrier()
#define SCHEDB()  __builtin_amdgcn_sched_barrier(0)

// ---------------------------------------------------------------------------
// R17 champion (1816 us) + NBUF 4->3 for 3 blocks/CU (single main variable).
// R17/R18 falsified LDS-volume & bank-conflict theories; the 33us/iter is
// phase-skeleton-bound (16x wait->bar->compute->bar->stage with 2 barrier
// groups/CU).  NBUF=3: LDS 48.3 KB -> 3 blocks/CU (144.9 KB); regs 52 VGPR +
// 32 AGPR = 84/wave, 6 waves/SIMD x 84 = 504 <= 512 unified file -> fits.
// A third independent barrier group/CU is the variable that mattered in
// R12/R13/R15.  Worst case (doesn't fit): occupancy stays 2/CU = neutral.
// Schedule: pair-phases, %3 buffer indexing (stage bufs == computed bufs,
// barrier-protected), steady WAITVM(2) (1 tile flying across barriers,
// never drained in-loop), tail 2 -> 0.
// Keeps R17's LDS slot-rotation swizzle (read slot / source-chunk permute).
// Also: ex0 rewritten grid-stride (was 56us launch-bound for 25 MB).
// MODE: 0 = UZ, 1 = UZ first, 2 = Z-only final (writes y), 3 = setup, K=2048.
// ---------------------------------------------------------------------------
template <int MODE>
__global__ __launch_bounds__(512) void pc_gemm(
    const bf16_t* __restrict__ Aex, bf16_t* __restrict__ wrecT,
    bf16_t* __restrict__ woutP, bf16_t* __restrict__ wg,
    bf16_t* __restrict__ wc,
    const bf16_t* __restrict__ xbf, const float* __restrict__ bias_g,
    const float* __restrict__ bias_o,
    bf16_t* __restrict__ exnext, bf16_t* __restrict__ u,
    bf16_t* __restrict__ z, bf16_t* __restrict__ ey,
    float* __restrict__ yout, float* __restrict__ energy)
{
    __shared__ __align__(16) bf16_t sA[NBUF][BM * BK];
    __shared__ __align__(16) bf16_t sB[NBUF][BN * BK];
    __shared__ float red[8];

    const int t    = threadIdx.x;
    const int lane = t & 63;
    const int wave = t >> 6;        // 0..7
    const int wm   = wave >> 2;     // wave row (0..1) -> 64 rows
    const int wn   = wave & 3;      // wave col (0..3) -> 32 cols
    const int m0   = blockIdx.x * BM;
    const int lr   = lane & 15;
    // swizzled read slot (lane constant): s' = ((g + (row>>1)) & 3) * 8
    const int lkb  = (((lane >> 4) + ((lane >> 1) & 3)) & 3) * 8;

    int role, n0, K;
    const bf16_t *Aop, *Bop;
    if constexpr (MODE == 3) {
        role = (int)blockIdx.y >= 8; n0 = ((int)blockIdx.y & 7) * BN; K = HID;
        Aop = role ? woutP : wrecT;  Bop = wrecT;
    } else if constexpr (MODE == 2) {
        role = 1; n0 = (int)blockIdx.y * BN; K = DIN;
        Aop = Aex; Bop = wc;
    } else {
        role = (int)blockIdx.y >= 8; n0 = ((int)blockIdx.y & 7) * BN; K = DIN;
        Aop = Aex; Bop = role ? wc : wg;
    }

    f32x4 acc[4][2] = {};

    // staging: lane l of wave w writes LDS slot (row = w*16 + l/4, s = l&3)
    // linearly; slot must CONTAIN k-chunk g = (s - (row>>1))&3 (lane const)
    const int srow = wave * 16 + (lane >> 2);
    const int gsrc = ((lane & 3) - ((lane >> 3) & 3)) & 3;
    const int scol = gsrc * 8;
    const bf16_t* gA = Aop + (int64_t)(m0 + srow) * K + scol;
    const bf16_t* gB = Bop + (int64_t)(n0 + srow) * K + scol;

    auto stage = [&](int tile, int buf) {
        const int64_t ko = (int64_t)tile * BK;
        GLDS(gA + ko, &sA[buf][wave * 512]);
        GLDS(gB + ko, &sB[buf][wave * 512]);
    };

    auto compute = [&](int buf) {
        bf16x8 af[4], bfr[2];
#pragma unroll
        for (int mi = 0; mi < 4; ++mi)
            af[mi] = *reinterpret_cast<const bf16x8*>(
                &sA[buf][(wm * 64 + mi * 16 + lr) * BK + lkb]);
#pragma unroll
        for (int ni = 0; ni < 2; ++ni)
            bfr[ni] = *reinterpret_cast<const bf16x8*>(
                &sB[buf][(wn * 32 + ni * 16 + lr) * BK + lkb]);
#pragma unroll
        for (int mi = 0; mi < 4; ++mi)
#pragma unroll
            for (int ni = 0; ni < 2; ++ni)
                acc[mi][ni] = __builtin_amdgcn_mfma_f32_16x16x32_bf16(
                    af[mi], bfr[ni], acc[mi][ni], 0, 0, 0);
    };

    const int ntile = K / BK;              // 32 (UZ) or 64 (setup)
    const int nph   = ntile / 2;           // 16 or 32
    stage(0, 0); stage(1, 1); stage(2, 2); // 6 loads in flight

    for (int p = 0; p < nph - 2; ++p) {
        const int t0 = 2 * p;
        WAITVM(2);               // tiles t0, t0+1 landed; t0+2 still flying
        BAR();
        SCHEDB();
        compute(t0 % 3);
        compute((t0 + 1) % 3);
        BAR();                   // all waves done with these two buffers
        stage(t0 + 3, t0 % 3);   // restage the exact buffers just computed
        stage(t0 + 4, (t0 + 1) % 3);
    }
    {   // p = nph-2: compute ntile-4, ntile-3; stage final tile ntile-1
        const int t0 = ntile - 4;
        WAITVM(2); BAR(); SCHEDB();
        compute(t0 % 3); compute((t0 + 1) % 3);
        BAR();
        stage(ntile - 1, (ntile - 1) % 3);
    }
    {   // last pair
        const int t0 = ntile - 2;
        WAITVM(0); BAR(); SCHEDB();
        compute(t0 % 3); compute((t0 + 1) % 3);
    }

    // epilogue: C mapping col=lane&15, row=(lane>>4)*4+j
    float esum = 0.0f;
    const int prow = (lane >> 4) * 4;
#pragma unroll
    for (int mi = 0; mi < 4; ++mi) {
#pragma unroll
        for (int ni = 0; ni < 2; ++ni) {
            const int col = n0 + wn * 32 + ni * 16 + lr;
#pragma unroll
            for (int j = 0; j < 4; ++j) {
                const int row = m0 + wm * 64 + mi * 16 + prow + j;
                const float v = acc[mi][ni][j];
                if constexpr (MODE == 3) {
                    bf16_t* cout = role ? wc : wg;
                    cout[(int64_t)row * 1024 + col] = (bf16_t)v;
                } else {
                    if (role == 0) {
                        // U role: u += LR*v; e_x' = x - sigmoid(u); energy
                        const int64_t idx = (int64_t)row * DIN + col;
                        const float D  = LR * v;
                        const float un =
                            (MODE == 1 ? bias_g[col] : (float)u[idx]) + D;
                        u[idx] = (bf16_t)un;
                        const float xp = 1.0f / (1.0f + __expf(-un));
                        const float e  = (float)xbf[idx] - xp;
                        exnext[idx] = (bf16_t)e;
                        esum += e * e;
                    } else if (col < DOUT) {
                        // Z role: z += D; e_y = (1+LR)e_y - D; energy
                        const int64_t idx = (int64_t)row * 1024 + col;
                        const float D  = LR * v;
                        const float zn =
                            (MODE == 1 ? bias_o[col] : (float)z[idx]) + D;
                        const float eyn = (MODE == 1)
                            ? -zn
                            : (1.0f + LR) * (float)ey[idx] - D;
                        if constexpr (MODE == 2) {
                            yout[(int64_t)row * DOUT + col] =
                                (1.0f + LR) * eyn + zn;
                        } else {
                            z[idx]  = (bf16_t)zn;
                            ey[idx] = (bf16_t)eyn;
                        }
                        esum += eyn * eyn;
                    }
                }
            }
        }
    }
    if constexpr (MODE != 3) {
#pragma unroll
        for (int off = 32; off; off >>= 1) esum += __shfl_down(esum, off, 64);
        if (lane == 0) red[wave] = esum;
        __syncthreads();
        if (t == 0) {
            float s = 0.0f;
#pragma unroll
            for (int w = 0; w < 8; ++w) s += red[w];
            atomicAdd(energy, s);
        }
    }
}

// W_rec [HID][DIN] f32 -> bf16 transpose [DIN][HID]
__global__ void conv_wrec(const float* __restrict__ W, bf16_t* __restrict__ WbT)
{
    __shared__ float tile[32][33];
    const int tx = threadIdx.x & 31;
    const int ty = threadIdx.x >> 5; // 0..7
    const int c0 = blockIdx.x * 32;  // DIN
    const int r0 = blockIdx.y * 32;  // HID
#pragma unroll
    for (int rr = ty; rr < 32; rr += 8)
        tile[rr][tx] = W[(int64_t)(r0 + rr) * DIN + c0 + tx];
    __syncthreads();
#pragma unroll
    for (int rr = ty; rr < 32; rr += 8)
        WbT[(int64_t)(c0 + rr) * HID + r0 + tx] = (bf16_t)tile[tx][rr];
}

// W_out [DOUT][HID] f32 -> bf16 [1024][HID], rows >= DOUT zero-padded
__global__ void conv_wout(const float* __restrict__ W, bf16_t* __restrict__ Wb)
{
    const int i = blockIdx.x * 256 + threadIdx.x; // over 1024*2048
    const int r = i >> 11;
    const int c = i & 2047;
    Wb[i] = (r < DOUT) ? (bf16_t)W[(int64_t)r * HID + c] : (bf16_t)0.0f;
}

// iteration 0: e_x0 = x - sigmoid(b_gen) (+ energy); also x -> bf16 copy.
// Grid-stride: 1024 blocks x 256 thr x 16 elems (was 4096 blocks @ 4 elems,
// launch/latency-bound at 56us for 25 MB).
__global__ void ex0_kernel(const float* __restrict__ x,
                           const float* __restrict__ bias_g,
                           bf16_t* __restrict__ ex, bf16_t* __restrict__ xbf,
                           float* __restrict__ energy)
{
    __shared__ float red[4];
    const int t = threadIdx.x, lane = t & 63, wave = t >> 6;
    float esum = 0.0f;
#pragma unroll
    for (int c = 0; c < 4; ++c) {
        const int i = ((blockIdx.x * 4 + c) * 256 + t) * 4;
        const int c0 = i & (DIN - 1);
        const float4 v = *reinterpret_cast<const float4*>(&x[i]);
        bf16x4 xo = {(bf16_t)v.x, (bf16_t)v.y, (bf16_t)v.z, (bf16_t)v.w};
        *reinterpret_cast<bf16x4*>(&xbf[i]) = xo;
        float e[4];
        const float b0 = bias_g[c0], b1 = bias_g[c0 + 1],
                    b2 = bias_g[c0 + 2], b3 = bias_g[c0 + 3];
        e[0] = v.x - 1.0f / (1.0f + __expf(-b0));
        e[1] = v.y - 1.0f / (1.0f + __expf(-b1));
        e[2] = v.z - 1.0f / (1.0f + __expf(-b2));
        e[3] = v.w - 1.0f / (1.0f + __expf(-b3));
        bf16x4 o = {(bf16_t)e[0], (bf16_t)e[1], (bf16_t)e[2], (bf16_t)e[3]};
        *reinterpret_cast<bf16x4*>(&ex[i]) = o;
        esum += e[0]*e[0] + e[1]*e[1] + e[2]*e[2] + e[3]*e[3];
    }
#pragma unroll
    for (int off = 32; off; off >>= 1) esum += __shfl_down(esum, off, 64);
    if (lane == 0) red[wave] = esum;
    __syncthreads();
    if (t == 0) atomicAdd(energy, red[0] + red[1] + red[2] + red[3]);
}

__global__ void finalize_kernel(const float* __restrict__ energy,
                                float* __restrict__ out)
{
    out[0] = energy[0] * (1.0f / ((float)BATCH * (float)NITER));
}

extern "C" void kernel_launch(void* const* d_in, const int* in_sizes, int n_in,
                              void* d_out, int out_size, void* d_ws, size_t ws_size,
                              hipStream_t stream)
{
    (void)in_sizes; (void)n_in; (void)out_size; (void)ws_size;
    const float* x        = (const float*)d_in[0];
    const float* W_rec    = (const float*)d_in[1];
    const float* W_out    = (const float*)d_in[2];
    const float* bias_out = (const float*)d_in[3];
    const float* bias_gen = (const float*)d_in[4];
    float* y = (float*)d_out; // [BATCH*DOUT] then [1] energy

    char* ws = (char*)d_ws;
    size_t off = 0;
    bf16_t* u     = (bf16_t*)(ws + off);  off += (size_t)BATCH * DIN * 2;   // 8 MB
    bf16_t* z     = (bf16_t*)(ws + off);  off += (size_t)BATCH * 1024 * 2;  // 8 MB
    bf16_t* exA   = (bf16_t*)(ws + off);  off += (size_t)BATCH * DIN * 2;   // 8 MB
    bf16_t* exB   = (bf16_t*)(ws + off);  off += (size_t)BATCH * DIN * 2;   // 8 MB
    bf16_t* ey    = (bf16_t*)(ws + off);  off += (size_t)BATCH * 1024 * 2;  // 8 MB
    bf16_t* xbf   = (bf16_t*)(ws + off);  off += (size_t)BATCH * DIN * 2;   // 8 MB
    bf16_t* wrecT = (bf16_t*)(ws + off);  off += (size_t)DIN * HID * 2;     // 4 MB
    bf16_t* woutP = (bf16_t*)(ws + off);  off += (size_t)1024 * HID * 2;    // 4 MB
    bf16_t* wg    = (bf16_t*)(ws + off);  off += (size_t)1024 * 1024 * 2;   // 2 MB
    bf16_t* wc    = (bf16_t*)(ws + off);  off += (size_t)1024 * 1024 * 2;   // 2 MB
    float* energy = (float*)(ws + off);   off += 256;                       // 60 MB

    hipMemsetAsync(energy, 0, 4, stream);

    conv_wrec<<<dim3(DIN / 32, HID / 32), 256, 0, stream>>>(W_rec, wrecT);
    conv_wout<<<(1024 * HID) / 256, 256, 0, stream>>>(W_out, woutP);
    // setup: Wg = W_rec^T W_rec (y<8), Wc = W_out W_rec (y>=8), K = 2048
    pc_gemm<3><<<dim3(8, 16), 512, 0, stream>>>(
        nullptr, wrecT, woutP, wg, wc, nullptr, nullptr, nullptr,
        nullptr, nullptr, nullptr, nullptr, nullptr, nullptr);

    ex0_kernel<<<dim3(1024), 256, 0, stream>>>(x, bias_gen, exA, xbf, energy);

    bf16_t* exbuf[2] = {exA, exB};
    for (int it = 0; it < NITER; ++it) {
        const bf16_t* src = exbuf[it & 1];
        bf16_t* dst = exbuf[(it & 1) ^ 1];
        if (it == 0)
            pc_gemm<1><<<dim3(BATCH / BM, 16), 512, 0, stream>>>(
                src, nullptr, nullptr, wg, wc, xbf, bias_gen, bias_out,
                dst, u, z, ey, nullptr, energy);
        else if (it < NITER - 1)
            pc_gemm<0><<<dim3(BATCH / BM, 16), 512, 0, stream>>>(
                src, nullptr, nullptr, wg, wc, xbf, bias_gen, bias_out,
                dst, u, z, ey, nullptr, energy);
        else
            pc_gemm<2><<<dim3(BATCH / BM, 8), 512, 0, stream>>>(
                src, nullptr, nullptr, wg, wc, xbf, bias_gen, bias_out,
                nullptr, u, z, ey, y, energy);
    }
    finalize_kernel<<<1, 1, 0, stream>>>(energy, y + (size_t)BATCH * DOUT);
}

// Round 20
// 1778.647 us; speedup vs baseline: 1.1592x; 1.0844x over previous
//
#include <hip/hip_runtime.h>
#include <hip/hip_bf16.h>
#include <cstdint>

typedef __bf16 bf16_t;
typedef __bf16 bf16x4 __attribute__((ext_vector_type(4)));
typedef __bf16 bf16x8 __attribute__((ext_vector_type(8)));
typedef float f32x4 __attribute__((ext_vector_type(4)));

#define BATCH 4096
#define DIN   1024
#define HID   2048
#define DOUT  1000
#define NITER 50
#define LR    0.001f

#define BM 128
#define BN 128
#define BK 32
#define NBUF 4

// async global -> LDS, 16 B per lane. LDS dest is wave-uniform base + lane*16.
#define GLDS(g, l)                                                        \
    __builtin_amdgcn_global_load_lds(                                     \
        (const __attribute__((address_space(1))) void*)(g),               \
        (__attribute__((address_space(3))) void*)(l), 16, 0, 0)

#define WAITVM(N) asm volatile("s_waitcnt vmcnt(" #N ")" ::: "memory")
#define BAR()     __builtin_amdgcn_s_barrier()
#define SCHEDB()  __builtin_amdgcn_sched_barrier(0)

// ---------------------------------------------------------------------------
// R20 = R17 champion pc_gemm (1816 us) + R19's proven ex0 grid-stride fix.
// R19 falsified NBUF=3 (depth-2 prefetch > 3rd barrier group); R18 falsified
// fp8 (LDS volume not the limiter); R16/R17 pinned bank conflicts at 0 via
// the slot-rotation swizzle.  This round recombines proven pieces only.
// pc_gemm: 512 thr / 8 waves (2x4), wave tile 64x32 acc[4][2], NBUF=4,
// two K-tiles per barrier pair, counted vmcnt (steady 4 = 2 tiles in flight,
// tail 4->0), LDS slot-rotation swizzle (read slot + source-chunk permute).
// States bf16 (u, z, ey, xbf); energy from f32 pre-quantization.
// MODE: 0 = UZ, 1 = UZ first (seed biases), 2 = Z-only final (writes y),
//       3 = setup (Wg = W_rec^T W_rec | Wc = W_out W_rec), K = 2048.
// ---------------------------------------------------------------------------
template <int MODE>
__global__ __launch_bounds__(512) void pc_gemm(
    const bf16_t* __restrict__ Aex, bf16_t* __restrict__ wrecT,
    bf16_t* __restrict__ woutP, bf16_t* __restrict__ wg,
    bf16_t* __restrict__ wc,
    const bf16_t* __restrict__ xbf, const float* __restrict__ bias_g,
    const float* __restrict__ bias_o,
    bf16_t* __restrict__ exnext, bf16_t* __restrict__ u,
    bf16_t* __restrict__ z, bf16_t* __restrict__ ey,
    float* __restrict__ yout, float* __restrict__ energy)
{
    __shared__ __align__(16) bf16_t sA[NBUF][BM * BK];
    __shared__ __align__(16) bf16_t sB[NBUF][BN * BK];
    __shared__ float red[8];

    const int t    = threadIdx.x;
    const int lane = t & 63;
    const int wave = t >> 6;        // 0..7
    const int wm   = wave >> 2;     // wave row (0..1) -> 64 rows
    const int wn   = wave & 3;      // wave col (0..3) -> 32 cols
    const int m0   = blockIdx.x * BM;
    const int lr   = lane & 15;
    // swizzled read slot (lane constant): s' = ((g + (row>>1)) & 3) * 8
    const int lkb  = (((lane >> 4) + ((lane >> 1) & 3)) & 3) * 8;

    int role, n0, K;
    const bf16_t *Aop, *Bop;
    if constexpr (MODE == 3) {
        role = (int)blockIdx.y >= 8; n0 = ((int)blockIdx.y & 7) * BN; K = HID;
        Aop = role ? woutP : wrecT;  Bop = wrecT;
    } else if constexpr (MODE == 2) {
        role = 1; n0 = (int)blockIdx.y * BN; K = DIN;
        Aop = Aex; Bop = wc;
    } else {
        role = (int)blockIdx.y >= 8; n0 = ((int)blockIdx.y & 7) * BN; K = DIN;
        Aop = Aex; Bop = role ? wc : wg;
    }

    f32x4 acc[4][2] = {};

    // staging: lane l of wave w writes LDS slot (row = w*16 + l/4, s = l&3)
    // linearly; slot must CONTAIN k-chunk g = (s - (row>>1))&3 (lane const)
    const int srow = wave * 16 + (lane >> 2);
    const int gsrc = ((lane & 3) - ((lane >> 3) & 3)) & 3;
    const int scol = gsrc * 8;
    const bf16_t* gA = Aop + (int64_t)(m0 + srow) * K + scol;
    const bf16_t* gB = Bop + (int64_t)(n0 + srow) * K + scol;

    auto stage = [&](int tile, int buf) {
        const int64_t ko = (int64_t)tile * BK;
        GLDS(gA + ko, &sA[buf][wave * 512]);
        GLDS(gB + ko, &sB[buf][wave * 512]);
    };

    auto compute = [&](int buf) {
        bf16x8 af[4], bfr[2];
#pragma unroll
        for (int mi = 0; mi < 4; ++mi)
            af[mi] = *reinterpret_cast<const bf16x8*>(
                &sA[buf][(wm * 64 + mi * 16 + lr) * BK + lkb]);
#pragma unroll
        for (int ni = 0; ni < 2; ++ni)
            bfr[ni] = *reinterpret_cast<const bf16x8*>(
                &sB[buf][(wn * 32 + ni * 16 + lr) * BK + lkb]);
#pragma unroll
        for (int mi = 0; mi < 4; ++mi)
#pragma unroll
            for (int ni = 0; ni < 2; ++ni)
                acc[mi][ni] = __builtin_amdgcn_mfma_f32_16x16x32_bf16(
                    af[mi], bfr[ni], acc[mi][ni], 0, 0, 0);
    };

    const int npairs = (K / BK) / 2;       // 16 (UZ) or 32 (setup)
    stage(0, 0); stage(1, 1); stage(2, 2); stage(3, 3);

    for (int p = 0; p < npairs - 2; ++p) {
        const int t0 = 2 * p;
        WAITVM(4);               // pair p landed; pair p+1 still flying
        BAR();
        SCHEDB();
        compute(t0 & 3);
        compute((t0 + 1) & 3);
        BAR();
        stage(t0 + 4, t0 & 3);   // vmcnt never drains to 0 in loop
        stage(t0 + 5, (t0 + 1) & 3);
    }
    {
        const int t0 = 2 * npairs - 4;
        WAITVM(4); BAR(); SCHEDB();
        compute(t0 & 3); compute((t0 + 1) & 3);
    }
    {
        const int t0 = 2 * npairs - 2;
        WAITVM(0); BAR(); SCHEDB();
        compute(t0 & 3); compute((t0 + 1) & 3);
    }

    // epilogue: C mapping col=lane&15, row=(lane>>4)*4+j
    float esum = 0.0f;
    const int prow = (lane >> 4) * 4;
#pragma unroll
    for (int mi = 0; mi < 4; ++mi) {
#pragma unroll
        for (int ni = 0; ni < 2; ++ni) {
            const int col = n0 + wn * 32 + ni * 16 + lr;
#pragma unroll
            for (int j = 0; j < 4; ++j) {
                const int row = m0 + wm * 64 + mi * 16 + prow + j;
                const float v = acc[mi][ni][j];
                if constexpr (MODE == 3) {
                    bf16_t* cout = role ? wc : wg;
                    cout[(int64_t)row * 1024 + col] = (bf16_t)v;
                } else {
                    if (role == 0) {
                        // U role: u += LR*v; e_x' = x - sigmoid(u); energy
                        const int64_t idx = (int64_t)row * DIN + col;
                        const float D  = LR * v;
                        const float un =
                            (MODE == 1 ? bias_g[col] : (float)u[idx]) + D;
                        u[idx] = (bf16_t)un;
                        const float xp = 1.0f / (1.0f + __expf(-un));
                        const float e  = (float)xbf[idx] - xp;
                        exnext[idx] = (bf16_t)e;
                        esum += e * e;
                    } else if (col < DOUT) {
                        // Z role: z += D; e_y = (1+LR)e_y - D; energy
                        const int64_t idx = (int64_t)row * 1024 + col;
                        const float D  = LR * v;
                        const float zn =
                            (MODE == 1 ? bias_o[col] : (float)z[idx]) + D;
                        const float eyn = (MODE == 1)
                            ? -zn
                            : (1.0f + LR) * (float)ey[idx] - D;
                        if constexpr (MODE == 2) {
                            yout[(int64_t)row * DOUT + col] =
                                (1.0f + LR) * eyn + zn;
                        } else {
                            z[idx]  = (bf16_t)zn;
                            ey[idx] = (bf16_t)eyn;
                        }
                        esum += eyn * eyn;
                    }
                }
            }
        }
    }
    if constexpr (MODE != 3) {
#pragma unroll
        for (int off = 32; off; off >>= 1) esum += __shfl_down(esum, off, 64);
        if (lane == 0) red[wave] = esum;
        __syncthreads();
        if (t == 0) {
            float s = 0.0f;
#pragma unroll
            for (int w = 0; w < 8; ++w) s += red[w];
            atomicAdd(energy, s);
        }
    }
}

// W_rec [HID][DIN] f32 -> bf16 transpose [DIN][HID]
__global__ void conv_wrec(const float* __restrict__ W, bf16_t* __restrict__ WbT)
{
    __shared__ float tile[32][33];
    const int tx = threadIdx.x & 31;
    const int ty = threadIdx.x >> 5; // 0..7
    const int c0 = blockIdx.x * 32;  // DIN
    const int r0 = blockIdx.y * 32;  // HID
#pragma unroll
    for (int rr = ty; rr < 32; rr += 8)
        tile[rr][tx] = W[(int64_t)(r0 + rr) * DIN + c0 + tx];
    __syncthreads();
#pragma unroll
    for (int rr = ty; rr < 32; rr += 8)
        WbT[(int64_t)(c0 + rr) * HID + r0 + tx] = (bf16_t)tile[tx][rr];
}

// W_out [DOUT][HID] f32 -> bf16 [1024][HID], rows >= DOUT zero-padded
__global__ void conv_wout(const float* __restrict__ W, bf16_t* __restrict__ Wb)
{
    const int i = blockIdx.x * 256 + threadIdx.x; // over 1024*2048
    const int r = i >> 11;
    const int c = i & 2047;
    Wb[i] = (r < DOUT) ? (bf16_t)W[(int64_t)r * HID + c] : (bf16_t)0.0f;
}

// iteration 0: e_x0 = x - sigmoid(b_gen) (+ energy); also x -> bf16 copy.
// Grid-stride: 1024 blocks x 256 thr x 16 elems (R19-proven, ~12us).
__global__ void ex0_kernel(const float* __restrict__ x,
                           const float* __restrict__ bias_g,
                           bf16_t* __restrict__ ex, bf16_t* __restrict__ xbf,
                           float* __restrict__ energy)
{
    __shared__ float red[4];
    const int t = threadIdx.x, lane = t & 63, wave = t >> 6;
    float esum = 0.0f;
#pragma unroll
    for (int c = 0; c < 4; ++c) {
        const int i = ((blockIdx.x * 4 + c) * 256 + t) * 4;
        const int c0 = i & (DIN - 1);
        const float4 v = *reinterpret_cast<const float4*>(&x[i]);
        bf16x4 xo = {(bf16_t)v.x, (bf16_t)v.y, (bf16_t)v.z, (bf16_t)v.w};
        *reinterpret_cast<bf16x4*>(&xbf[i]) = xo;
        float e[4];
        const float b0 = bias_g[c0], b1 = bias_g[c0 + 1],
                    b2 = bias_g[c0 + 2], b3 = bias_g[c0 + 3];
        e[0] = v.x - 1.0f / (1.0f + __expf(-b0));
        e[1] = v.y - 1.0f / (1.0f + __expf(-b1));
        e[2] = v.z - 1.0f / (1.0f + __expf(-b2));
        e[3] = v.w - 1.0f / (1.0f + __expf(-b3));
        bf16x4 o = {(bf16_t)e[0], (bf16_t)e[1], (bf16_t)e[2], (bf16_t)e[3]};
        *reinterpret_cast<bf16x4*>(&ex[i]) = o;
        esum += e[0]*e[0] + e[1]*e[1] + e[2]*e[2] + e[3]*e[3];
    }
#pragma unroll
    for (int off = 32; off; off >>= 1) esum += __shfl_down(esum, off, 64);
    if (lane == 0) red[wave] = esum;
    __syncthreads();
    if (t == 0) atomicAdd(energy, red[0] + red[1] + red[2] + red[3]);
}

__global__ void finalize_kernel(const float* __restrict__ energy,
                                float* __restrict__ out)
{
    out[0] = energy[0] * (1.0f / ((float)BATCH * (float)NITER));
}

extern "C" void kernel_launch(void* const* d_in, const int* in_sizes, int n_in,
                              void* d_out, int out_size, void* d_ws, size_t ws_size,
                              hipStream_t stream)
{
    (void)in_sizes; (void)n_in; (void)out_size; (void)ws_size;
    const float* x        = (const float*)d_in[0];
    const float* W_rec    = (const float*)d_in[1];
    const float* W_out    = (const float*)d_in[2];
    const float* bias_out = (const float*)d_in[3];
    const float* bias_gen = (const float*)d_in[4];
    float* y = (float*)d_out; // [BATCH*DOUT] then [1] energy

    char* ws = (char*)d_ws;
    size_t off = 0;
    bf16_t* u     = (bf16_t*)(ws + off);  off += (size_t)BATCH * DIN * 2;   // 8 MB
    bf16_t* z     = (bf16_t*)(ws + off);  off += (size_t)BATCH * 1024 * 2;  // 8 MB
    bf16_t* exA   = (bf16_t*)(ws + off);  off += (size_t)BATCH * DIN * 2;   // 8 MB
    bf16_t* exB   = (bf16_t*)(ws + off);  off += (size_t)BATCH * DIN * 2;   // 8 MB
    bf16_t* ey    = (bf16_t*)(ws + off);  off += (size_t)BATCH * 1024 * 2;  // 8 MB
    bf16_t* xbf   = (bf16_t*)(ws + off);  off += (size_t)BATCH * DIN * 2;   // 8 MB
    bf16_t* wrecT = (bf16_t*)(ws + off);  off += (size_t)DIN * HID * 2;     // 4 MB
    bf16_t* woutP = (bf16_t*)(ws + off);  off += (size_t)1024 * HID * 2;    // 4 MB
    bf16_t* wg    = (bf16_t*)(ws + off);  off += (size_t)1024 * 1024 * 2;   // 2 MB
    bf16_t* wc    = (bf16_t*)(ws + off);  off += (size_t)1024 * 1024 * 2;   // 2 MB
    float* energy = (float*)(ws + off);   off += 256;                       // 60 MB

    hipMemsetAsync(energy, 0, 4, stream);

    conv_wrec<<<dim3(DIN / 32, HID / 32), 256, 0, stream>>>(W_rec, wrecT);
    conv_wout<<<(1024 * HID) / 256, 256, 0, stream>>>(W_out, woutP);
    // setup: Wg = W_rec^T W_rec (y<8), Wc = W_out W_rec (y>=8), K = 2048
    pc_gemm<3><<<dim3(8, 16), 512, 0, stream>>>(
        nullptr, wrecT, woutP, wg, wc, nullptr, nullptr, nullptr,
        nullptr, nullptr, nullptr, nullptr, nullptr, nullptr);

    ex0_kernel<<<dim3(1024), 256, 0, stream>>>(x, bias_gen, exA, xbf, energy);

    bf16_t* exbuf[2] = {exA, exB};
    for (int it = 0; it < NITER; ++it) {
        const bf16_t* src = exbuf[it & 1];
        bf16_t* dst = exbuf[(it & 1) ^ 1];
        if (it == 0)
            pc_gemm<1><<<dim3(BATCH / BM, 16), 512, 0, stream>>>(
                src, nullptr, nullptr, wg, wc, xbf, bias_gen, bias_out,
                dst, u, z, ey, nullptr, energy);
        else if (it < NITER - 1)
            pc_gemm<0><<<dim3(BATCH / BM, 16), 512, 0, stream>>>(
                src, nullptr, nullptr, wg, wc, xbf, bias_gen, bias_out,
                dst, u, z, ey, nullptr, energy);
        else
            pc_gemm<2><<<dim3(BATCH / BM, 8), 512, 0, stream>>>(
                src, nullptr, nullptr, wg, wc, xbf, bias_gen, bias_out,
                nullptr, u, z, ey, y, energy);
    }
    finalize_kernel<<<1, 1, 0, stream>>>(energy, y + (size_t)BATCH * DOUT);
}